// Round 7
// baseline (176.987 us; speedup 1.0000x reference)
//
#include <hip/hip_runtime.h>
#include <hip/hip_bf16.h>

// AngleProtoLoss: loss = -mean_n logsoftmax(clip(cos(last_n,cent_k),1e-6)*w+b)[n,n]
// Identity: loss_n = ln2*(log2(sum_k 2^{z_nk}) - z_nn), z = clamp(cos*w*log2e); b cancels.
// k1: centroids+norms -> unit cent (bf16), w*log2e-prescaled unit last (bf16), fp32 z_nn;
//     zeroes zsum.
// k2: bf16 MFMA 16x16x32, wave owns 64 rows (A in regs); B staged once per block via
//     global_load_lds (XOR chunk swizzle) into double-buffered LDS (B shared by 4 waves
//     -> 4x less L2 traffic than per-wave streaming; contiguous full-line DMA).
//     NO launch_bounds: rounds 4/5 showed min_waves>=3 makes the allocator split the
//     unified file (VGPR=64/84) and spill 126 MB to scratch. Grid (32,32): 1024 blocks,
//     ~4 blocks/CU so other blocks' compute masks each block's barrier/DMA drain.
// k3: single block: loss = ln2/N * sum_n (log2(zsum_n) - z_nn).

typedef __attribute__((ext_vector_type(8))) short short8;
typedef __attribute__((ext_vector_type(4))) float f32x4;

#define NSPK 8192
#define DEMB 128
#define MUTT 10
#define LOG2E 1.44269504088896340736f
#define LN2   0.69314718055994530942f

// workspace: floats [0,8192) = zdiag, [8192,16384) = zsum; then bf16 matrices
#define WS_ZDIAG 0
#define WS_ZSUM  8192
#define WS_LASTB 65536      // byte offset, 2 MB
#define WS_CENTB 2162688    // byte offset, 2 MB

__global__ __launch_bounds__(256) void k1_prep(const float* __restrict__ x,
                                               const float* __restrict__ wp,
                                               float* __restrict__ W,
                                               __hip_bfloat16* __restrict__ lastb,
                                               __hip_bfloat16* __restrict__ centb) {
    const int wv = threadIdx.x >> 6;
    const int l  = threadIdx.x & 63;
    const int n  = blockIdx.x * 4 + wv;           // one wave per speaker
    if (blockIdx.x < 32) W[WS_ZSUM + blockIdx.x * 256 + threadIdx.x] = 0.f;

    const float* xr = x + (size_t)n * (MUTT * DEMB) + 2 * l;   // lane owns dims 2l,2l+1
    float sx = 0.f, sy = 0.f, vx = 0.f, vy = 0.f;
#pragma unroll
    for (int m = 0; m < MUTT; ++m) {
        float2 t = *(const float2*)(xr + m * DEMB);
        vx = t.x; vy = t.y; sx += t.x; sy += t.y;
    }
    const float cx = sx * 0.1f, cy = sy * 0.1f;   // centroid dims
    float sl = vx * vx + vy * vy;                 // |last|^2 partial
    float sc = cx * cx + cy * cy;                 // |cent|^2 partial
    float dp = vx * cx + vy * cy;                 // last.cent partial (diag)
#pragma unroll
    for (int off = 1; off < 64; off <<= 1) {
        sl += __shfl_xor(sl, off);
        sc += __shfl_xor(sc, off);
        dp += __shfl_xor(dp, off);
    }
    const float il = rsqrtf(sl), ic = rsqrtf(sc);
    const float scale = wp[0] * LOG2E;
    const float as = il * scale;                  // prescale last by w*log2e
    __hip_bfloat162 lv, cv;
    lv.x = __float2bfloat16(vx * as); lv.y = __float2bfloat16(vy * as);
    cv.x = __float2bfloat16(cx * ic); cv.y = __float2bfloat16(cy * ic);
    *(__hip_bfloat162*)(lastb + n * DEMB + 2 * l) = lv;
    *(__hip_bfloat162*)(centb + n * DEMB + 2 * l) = cv;
    if (l == 0) {
        const float lo = scale >= 0.f ? 1e-6f * scale : -INFINITY;
        const float hi = scale >= 0.f ? INFINITY : 1e-6f * scale;
        W[WS_ZDIAG + n] = fminf(fmaxf(dp * il * ic * scale, lo), hi);
    }
}

// grid (32,32): 256-row block x 256-col chunk. 4 waves; wave owns 64 rows (4 row-tiles).
__global__ void k2_main(
        const __hip_bfloat16* __restrict__ lastb,
        const __hip_bfloat16* __restrict__ centb,
        const float* __restrict__ wp,
        float* __restrict__ W) {
    const int tid  = threadIdx.x;
    const int lane = tid & 63;
    const int wv   = tid >> 6;
    const int quad = lane >> 4;
    const int l16  = lane & 15;
    const int R0   = blockIdx.x * 256;
    const int C0   = blockIdx.y * 256;
    const float scale = wp[0] * LOG2E;
    const float lo = scale >= 0.f ? 1e-6f * scale : -INFINITY;
    const float hi = scale >= 0.f ? INFINITY : 1e-6f * scale;

    __shared__ uint4 Bs4[2048];   // 2 x 16 KB double buffer, XOR chunk-swizzled
    char* Bsc = (char*)Bs4;

    const int srow = wv * 16 + quad;          // staging row (+i*4)
    const int sp   = l16;                     // slot within row

    // prologue: DMA tile 0 into buf 0 (overlaps the A-frag loads below)
#pragma unroll
    for (int i = 0; i < 4; ++i) {
        const int row = srow + i * 4;
        const int c   = sp ^ (row & 15);
        const char* src = (const char*)centb + ((size_t)(C0 + row) << 8) + (c << 4);
        char* dst = Bsc + (wv * 4096 + i * 1024 + lane * 16);
        __builtin_amdgcn_global_load_lds(
            (const __attribute__((address_space(1))) unsigned int*)src,
            (__attribute__((address_space(3))) unsigned int*)dst, 16, 0, 0);
    }

    // A fragments (held whole kernel): rows R0 + wv*64 + rt*16 + l16, k = quad*8 + kc*32
    short8 a[4][4];
    {
        const short* ap = (const short*)lastb + (size_t)(R0 + wv * 64 + l16) * DEMB + quad * 8;
#pragma unroll
        for (int rt = 0; rt < 4; ++rt)
#pragma unroll
            for (int kc = 0; kc < 4; ++kc)
                a[rt][kc] = *(const short8*)(ap + rt * 16 * DEMB + kc * 32);
    }

    // swizzled B-fragment byte offsets within a 16-row ntile: row=l16, chunk=(quad+4kc)^l16
    int roff[4];
#pragma unroll
    for (int kc = 0; kc < 4; ++kc)
        roff[kc] = l16 * 256 + (((quad + 4 * kc) ^ l16) << 4);

    float racc[4][4] = {{0.f}};

    for (int it = 0; it < 4; ++it) {
        // drains vmcnt -> DMA(it) landed; also all waves done reading buf[(it+1)&1]
        __syncthreads();
        if (it < 3) {
            const int c0n = C0 + (it + 1) * 64;
            char* bufn = Bsc + ((it + 1) & 1) * 16384;
#pragma unroll
            for (int i = 0; i < 4; ++i) {
                const int row = srow + i * 4;
                const int c   = sp ^ (row & 15);
                const char* src = (const char*)centb + ((size_t)(c0n + row) << 8) + (c << 4);
                char* dst = bufn + (wv * 4096 + i * 1024 + lane * 16);
                __builtin_amdgcn_global_load_lds(
                    (const __attribute__((address_space(1))) unsigned int*)src,
                    (__attribute__((address_space(3))) unsigned int*)dst, 16, 0, 0);
            }
        }
        const char* buf = Bsc + (it & 1) * 16384;
#pragma unroll
        for (int nt = 0; nt < 4; ++nt) {
            short8 b[4];
#pragma unroll
            for (int kc = 0; kc < 4; ++kc)
                b[kc] = *(const short8*)(buf + nt * 4096 + roff[kc]);
#pragma unroll
            for (int rt = 0; rt < 4; ++rt) {
                f32x4 acc = {0.f, 0.f, 0.f, 0.f};
#pragma unroll
                for (int kc = 0; kc < 4; ++kc)
                    acc = __builtin_amdgcn_mfma_f32_16x16x32_bf16(a[rt][kc], b[kc], acc, 0, 0, 0);
                // C layout: col = l16, row = quad*4 + r; acc is already z (A prescaled)
#pragma unroll
                for (int r = 0; r < 4; ++r) {
                    const float z = fminf(fmaxf(acc[r], lo), hi);   // v_med3_f32
                    racc[rt][r] += __builtin_amdgcn_exp2f(z);
                }
            }
        }
    }
    // reduce row sums over the 16 l16-lanes holding the same rows
#pragma unroll
    for (int off = 1; off < 16; off <<= 1)
#pragma unroll
        for (int rt = 0; rt < 4; ++rt)
#pragma unroll
            for (int r = 0; r < 4; ++r)
                racc[rt][r] += __shfl_xor(racc[rt][r], off);
    if (l16 == 0) {
#pragma unroll
        for (int rt = 0; rt < 4; ++rt)
#pragma unroll
            for (int r = 0; r < 4; ++r)
                atomicAdd(&W[WS_ZSUM + R0 + wv * 64 + rt * 16 + quad * 4 + r], racc[rt][r]);
    }
}

__global__ __launch_bounds__(256) void k3_loss(const float* __restrict__ W,
                                               float* __restrict__ out) {
    float v = 0.f;
    for (int n = threadIdx.x; n < NSPK; n += 256)
        v += __log2f(W[WS_ZSUM + n]) - W[WS_ZDIAG + n];
#pragma unroll
    for (int off = 1; off < 64; off <<= 1) v += __shfl_xor(v, off);
    __shared__ float red[4];
    if ((threadIdx.x & 63) == 0) red[threadIdx.x >> 6] = v;
    __syncthreads();
    if (threadIdx.x == 0)
        out[0] = (red[0] + red[1] + red[2] + red[3]) * (LN2 / (float)NSPK);
}

extern "C" void kernel_launch(void* const* d_in, const int* in_sizes, int n_in,
                              void* d_out, int out_size, void* d_ws, size_t ws_size,
                              hipStream_t stream) {
    const float* x = (const float*)d_in[0];
    const float* w = (const float*)d_in[1];
    // b (d_in[2]) cancels analytically — unused.
    float* W = (float*)d_ws;
    __hip_bfloat16* lastb = (__hip_bfloat16*)((char*)d_ws + WS_LASTB);
    __hip_bfloat16* centb = (__hip_bfloat16*)((char*)d_ws + WS_CENTB);

    k1_prep<<<NSPK / 4, 256, 0, stream>>>(x, w, W, lastb, centb);
    k2_main<<<dim3(32, 32), 256, 0, stream>>>(lastb, centb, w, W);
    k3_loss<<<1, 256, 0, stream>>>(W, (float*)d_out);
}

// Round 8
// 114.574 us; speedup vs baseline: 1.5447x; 1.5447x over previous
//
#include <hip/hip_runtime.h>
#include <hip/hip_bf16.h>

// AngleProtoLoss: loss = -mean_n logsoftmax(clip(cos(last_n,cent_k),1e-6)*w+b)[n,n]
// Identity: loss_n = ln2*(log2(sum_k 2^{z_nk}) - z_nn), z = clamp(cos*w*log2e); b cancels.
// k1: centroids+norms -> unit cent (bf16), w*log2e-prescaled unit last (bf16), fp32 z_nn;
//     zeroes zsum.
// k2: bf16 MFMA 16x16x32. Wave owns 64 rows (A frags in regs). The block's WHOLE 256-col
//     B chunk (64 KB) is staged once via global_load_lds (src-side XOR chunk swizzle,
//     verified rounds 2-7) -> ONE __syncthreads per block (round 3 had 8 barrier+drains,
//     its k2 was ~30us vs ~8us matrix floor). 2 resident blocks/CU mask each other's
//     staging drain. __launch_bounds__(256,2) is MANDATORY: (256,3)/(256,4)/unbounded all
//     make the allocator split the unified file to 64-84 VGPRs -> 126-160 MB scratch
//     spill (rounds 4,5,7).
// k3: single block: loss = ln2/N * sum_n (log2(zsum_n) - z_nn).

typedef __attribute__((ext_vector_type(8))) short short8;
typedef __attribute__((ext_vector_type(4))) float f32x4;

#define NSPK 8192
#define DEMB 128
#define MUTT 10
#define LOG2E 1.44269504088896340736f
#define LN2   0.69314718055994530942f

// workspace: floats [0,8192) = zdiag, [8192,16384) = zsum; then bf16 matrices
#define WS_ZDIAG 0
#define WS_ZSUM  8192
#define WS_LASTB 65536      // byte offset, 2 MB
#define WS_CENTB 2162688    // byte offset, 2 MB

__global__ __launch_bounds__(256) void k1_prep(const float* __restrict__ x,
                                               const float* __restrict__ wp,
                                               float* __restrict__ W,
                                               __hip_bfloat16* __restrict__ lastb,
                                               __hip_bfloat16* __restrict__ centb) {
    const int wv = threadIdx.x >> 6;
    const int l  = threadIdx.x & 63;
    const int n  = blockIdx.x * 4 + wv;           // one wave per speaker
    if (blockIdx.x < 32) W[WS_ZSUM + blockIdx.x * 256 + threadIdx.x] = 0.f;

    const float* xr = x + (size_t)n * (MUTT * DEMB) + 2 * l;   // lane owns dims 2l,2l+1
    float sx = 0.f, sy = 0.f, vx = 0.f, vy = 0.f;
#pragma unroll
    for (int m = 0; m < MUTT; ++m) {
        float2 t = *(const float2*)(xr + m * DEMB);
        vx = t.x; vy = t.y; sx += t.x; sy += t.y;
    }
    const float cx = sx * 0.1f, cy = sy * 0.1f;   // centroid dims
    float sl = vx * vx + vy * vy;                 // |last|^2 partial
    float sc = cx * cx + cy * cy;                 // |cent|^2 partial
    float dp = vx * cx + vy * cy;                 // last.cent partial (diag)
#pragma unroll
    for (int off = 1; off < 64; off <<= 1) {
        sl += __shfl_xor(sl, off);
        sc += __shfl_xor(sc, off);
        dp += __shfl_xor(dp, off);
    }
    const float il = rsqrtf(sl), ic = rsqrtf(sc);
    const float scale = wp[0] * LOG2E;
    const float as = il * scale;                  // prescale last by w*log2e
    __hip_bfloat162 lv, cv;
    lv.x = __float2bfloat16(vx * as); lv.y = __float2bfloat16(vy * as);
    cv.x = __float2bfloat16(cx * ic); cv.y = __float2bfloat16(cy * ic);
    *(__hip_bfloat162*)(lastb + n * DEMB + 2 * l) = lv;
    *(__hip_bfloat162*)(centb + n * DEMB + 2 * l) = cv;
    if (l == 0) {
        const float lo = scale >= 0.f ? 1e-6f * scale : -INFINITY;
        const float hi = scale >= 0.f ? INFINITY : 1e-6f * scale;
        W[WS_ZDIAG + n] = fminf(fmaxf(dp * il * ic * scale, lo), hi);
    }
}

// grid (32,32): 256-row block x 256-col chunk. 4 waves; wave owns 64 rows (4 row-tiles).
// Whole 64 KB B chunk staged once; ONE barrier; 16 ntiles of uninterrupted MFMA.
__global__ __launch_bounds__(256, 2) void k2_main(
        const __hip_bfloat16* __restrict__ lastb,
        const __hip_bfloat16* __restrict__ centb,
        const float* __restrict__ wp,
        float* __restrict__ W) {
    const int tid  = threadIdx.x;
    const int lane = tid & 63;
    const int wv   = tid >> 6;
    const int quad = lane >> 4;
    const int l16  = lane & 15;
    const int R0   = blockIdx.x * 256;
    const int C0   = blockIdx.y * 256;
    const float scale = wp[0] * LOG2E;
    const float lo = scale >= 0.f ? 1e-6f * scale : -INFINITY;
    const float hi = scale >= 0.f ? INFINITY : 1e-6f * scale;

    __shared__ uint4 Bs4[4096];   // 64 KB: 256 rows x 16 chunks of 16B, XOR-swizzled
    char* Bsc = (char*)Bs4;

    // stage the whole 256-col x 128-dim B chunk: 16 rounds x 4 KB.
    // round i: thread tid -> LDS row r = i*16 + (tid>>4), slot = tid&15;
    // slot holds GLOBAL chunk (slot ^ (r&15)) — swizzle is src-side, dst stays
    // the DMA-mandated wave-uniform base + lane*16 (dst = i*4096 + tid*16 = r*256 + slot*16).
#pragma unroll
    for (int i = 0; i < 16; ++i) {
        const int r = i * 16 + (tid >> 4);
        const int c = (tid & 15) ^ (r & 15);
        const char* src = (const char*)centb + ((size_t)(C0 + r) << 8) + (c << 4);
        char* dst = Bsc + i * 4096 + tid * 16;
        __builtin_amdgcn_global_load_lds(
            (const __attribute__((address_space(1))) unsigned int*)src,
            (__attribute__((address_space(3))) unsigned int*)dst, 16, 0, 0);
    }

    // A fragments (held whole kernel): rows R0 + wv*64 + rt*16 + l16, k = quad*8 + kc*32
    short8 a[4][4];
    {
        const short* ap = (const short*)lastb + (size_t)(R0 + wv * 64 + l16) * DEMB + quad * 8;
#pragma unroll
        for (int rt = 0; rt < 4; ++rt)
#pragma unroll
            for (int kc = 0; kc < 4; ++kc)
                a[rt][kc] = *(const short8*)(ap + rt * 16 * DEMB + kc * 32);
    }

    // swizzled B-fragment byte offsets within a 16-row ntile: row=l16, chunk=(quad+4kc)^l16
    int roff[4];
#pragma unroll
    for (int kc = 0; kc < 4; ++kc)
        roff[kc] = l16 * 256 + (((quad + 4 * kc) ^ l16) << 4);

    float racc[4][4] = {{0.f}};

    __syncthreads();   // the ONLY barrier: drains DMA, B tile visible to all waves

#pragma unroll 4
    for (int nt = 0; nt < 16; ++nt) {
        short8 b[4];
#pragma unroll
        for (int kc = 0; kc < 4; ++kc)
            b[kc] = *(const short8*)(Bsc + nt * 4096 + roff[kc]);
#pragma unroll
        for (int rt = 0; rt < 4; ++rt) {
            f32x4 acc = {0.f, 0.f, 0.f, 0.f};
#pragma unroll
            for (int kc = 0; kc < 4; ++kc)
                acc = __builtin_amdgcn_mfma_f32_16x16x32_bf16(a[rt][kc], b[kc], acc, 0, 0, 0);
            // C layout: col = l16, row = quad*4 + r; acc is already z (A prescaled)
#pragma unroll
            for (int r = 0; r < 4; ++r) {
                const float z = fminf(fmaxf(acc[r], lo), hi);   // v_med3_f32
                racc[rt][r] += __builtin_amdgcn_exp2f(z);
            }
        }
    }
    // reduce row sums over the 16 l16-lanes holding the same rows
#pragma unroll
    for (int off = 1; off < 16; off <<= 1)
#pragma unroll
        for (int rt = 0; rt < 4; ++rt)
#pragma unroll
            for (int r = 0; r < 4; ++r)
                racc[rt][r] += __shfl_xor(racc[rt][r], off);
    if (l16 == 0) {
#pragma unroll
        for (int rt = 0; rt < 4; ++rt)
#pragma unroll
            for (int r = 0; r < 4; ++r)
                atomicAdd(&W[WS_ZSUM + R0 + wv * 64 + rt * 16 + quad * 4 + r], racc[rt][r]);
    }
}

__global__ __launch_bounds__(256) void k3_loss(const float* __restrict__ W,
                                               float* __restrict__ out) {
    float v = 0.f;
    for (int n = threadIdx.x; n < NSPK; n += 256)
        v += __log2f(W[WS_ZSUM + n]) - W[WS_ZDIAG + n];
#pragma unroll
    for (int off = 1; off < 64; off <<= 1) v += __shfl_xor(v, off);
    __shared__ float red[4];
    if ((threadIdx.x & 63) == 0) red[threadIdx.x >> 6] = v;
    __syncthreads();
    if (threadIdx.x == 0)
        out[0] = (red[0] + red[1] + red[2] + red[3]) * (LN2 / (float)NSPK);
}

extern "C" void kernel_launch(void* const* d_in, const int* in_sizes, int n_in,
                              void* d_out, int out_size, void* d_ws, size_t ws_size,
                              hipStream_t stream) {
    const float* x = (const float*)d_in[0];
    const float* w = (const float*)d_in[1];
    // b (d_in[2]) cancels analytically — unused.
    float* W = (float*)d_ws;
    __hip_bfloat16* lastb = (__hip_bfloat16*)((char*)d_ws + WS_LASTB);
    __hip_bfloat16* centb = (__hip_bfloat16*)((char*)d_ws + WS_CENTB);

    k1_prep<<<NSPK / 4, 256, 0, stream>>>(x, w, W, lastb, centb);
    k2_main<<<dim3(32, 32), 256, 0, stream>>>(lastb, centb, w, W);
    k3_loss<<<1, 256, 0, stream>>>(W, (float*)d_out);
}